// Round 1
// baseline (117.681 us; speedup 1.0000x reference)
//
#include <hip/hip_runtime.h>

// LocalitySensitiveHashing_29111288333011
//
// Analytical collapse: sim = mean_h( qh[b,q,h,k] * kh[b,k,h,k] ) / HB with
// qh,kh in {-1,0,+1} and HB=2048, so |sim| <= 1/2048 ~= 4.9e-4 < 0.3
// threshold. Output (sim > 0.3).astype(f32) is identically zero.
// The kernel is therefore a pure 33.55 MB zero-fill of d_out (the harness
// poisons d_out to 0xAA before every timed launch, so the store is required).

__global__ void __launch_bounds__(256)
lsh_zero_out_kernel(float4* __restrict__ out4, int n4,
                    float* __restrict__ out_tail, int tail_base, int n_total) {
    const int stride = gridDim.x * blockDim.x;
    const float4 z = make_float4(0.0f, 0.0f, 0.0f, 0.0f);
    for (int i = blockIdx.x * blockDim.x + threadIdx.x; i < n4; i += stride) {
        out4[i] = z;
    }
    // Tail (out_size % 4 != 0) — not hit for this problem (8388608 % 4 == 0),
    // kept for generality.
    int t = tail_base + (blockIdx.x * blockDim.x + threadIdx.x);
    if (t < n_total) {
        out_tail[t] = 0.0f;
    }
}

extern "C" void kernel_launch(void* const* d_in, const int* in_sizes, int n_in,
                              void* d_out, int out_size, void* d_ws, size_t ws_size,
                              hipStream_t stream) {
    (void)d_in; (void)in_sizes; (void)n_in; (void)d_ws; (void)ws_size;

    const int n4 = out_size / 4;          // number of float4 stores
    const int tail_base = n4 * 4;         // first scalar-tail element

    const int block = 256;
    int grid = (n4 + block - 1) / block;
    if (grid > 2048) grid = 2048;         // grid-stride the rest (8 blocks/CU)
    if (grid < 1) grid = 1;

    lsh_zero_out_kernel<<<grid, block, 0, stream>>>(
        (float4*)d_out, n4, (float*)d_out, tail_base, out_size);
}